// Round 4
// baseline (248.873 us; speedup 1.0000x reference)
//
#include <hip/hip_runtime.h>
#include <stdint.h>

// B=32, Cin=128, T=4096, K=4, Cout=256, ks=7, pad=3
// v5: conv K-loop switched to mfma_f32_32x32x16_bf16 (half the MFMA instrs,
// +15% rate, frees ~50 VGPRs for compiler pipelining at the same 8 waves/CU).
// weff fragment layout updated to the 32x32 A-operand order (fold rewritten
// to match). Staging / pool / alpha logic unchanged from the passing v4.

// workspace offsets (bytes)
#define WEFF_OFF   0u          // bf16 folded W [b][cb][step56][ct][lane][8] -> 14,680,064 B
#define POOLED_OFF 14680064u   // fp32 [32][128]
#define BEFF_OFF   14696448u   // fp32 [32][256]

typedef short short8 __attribute__((ext_vector_type(8)));
typedef float f32x16 __attribute__((ext_vector_type(16)));

__device__ __forceinline__ unsigned short f2bf(float f) {
  unsigned int u = __builtin_bit_cast(unsigned int, f);
  u += 0x7fffu + ((u >> 16) & 1u);   // RNE
  return (unsigned short)(u >> 16);
}

// ---------------------------------------------------------------------------
// Kernel 1: pooled[b][ci] = sum_t x[b][ci][t]  (exact fp32, one block per row)
// ---------------------------------------------------------------------------
__global__ __launch_bounds__(256) void k_pool(const float* __restrict__ x,
                                              float* __restrict__ pooled) {
  __shared__ float ws4[4];
  int row = blockIdx.x;                       // b*128 + ci, 4096 rows
  const float* src = x + (size_t)row * 4096 + threadIdx.x * 16;
  float s = 0.f;
  #pragma unroll
  for (int i = 0; i < 4; ++i) {
    float4 v = *(const float4*)(src + i * 4);
    s += (v.x + v.y) + (v.z + v.w);
  }
  #pragma unroll
  for (int off = 32; off > 0; off >>= 1) s += __shfl_down(s, off);
  int lane = threadIdx.x & 63, wv = threadIdx.x >> 6;
  if (lane == 0) ws4[wv] = s;
  __syncthreads();
  if (threadIdx.x == 0) pooled[row] = (ws4[0] + ws4[1]) + (ws4[2] + ws4[3]);
}

// ---------------------------------------------------------------------------
// Kernel 2 (fold): alpha in-block (redundant, cheap), bias_eff (block 0),
// folded bf16 weights in 32x32-MFMA A-fragment order. Reads w ONCE (b-loop
// inside thread), native [k][cout][ci][s] layout.
//   weff_short8[((cb*56 + step)*4 + ct)*64 + lane], per-b stride 14336,
//   step = s*8 + slice, cout = cb*128 + ct*32 + (lane&31),
//   ci = slice*16 + (lane>>5)*8 + j.
// ---------------------------------------------------------------------------
__global__ __launch_bounds__(256) void k_fold(
    const float* __restrict__ w, const float* __restrict__ pooled,
    const float* __restrict__ rw, const float* __restrict__ rb,
    const float* __restrict__ bias, unsigned short* __restrict__ weff,
    float* __restrict__ bias_eff) {
  __shared__ float al[32][4];
  int tid = threadIdx.x;
  // --- alpha logits: 128 threads = 32 b x 4 k, serial length-128 dot ---
  if (tid < 128) {
    int b = tid >> 2, k = tid & 3;
    const float* pp = pooled + b * 128;
    const float* rwk = rw + k * 128;
    float s = rb[k];
    #pragma unroll 8
    for (int j = 0; j < 128; ++j) s += pp[j] * (1.0f / 4096.0f) * rwk[j];
    al[b][k] = s;
  }
  __syncthreads();
  if (tid < 32) {
    float l0 = al[tid][0], l1 = al[tid][1], l2 = al[tid][2], l3 = al[tid][3];
    float m = fmaxf(fmaxf(l0, l1), fmaxf(l2, l3));
    float e0 = __expf(l0 - m), e1 = __expf(l1 - m);
    float e2 = __expf(l2 - m), e3 = __expf(l3 - m);
    float inv = 1.0f / (e0 + e1 + e2 + e3);
    al[tid][0] = e0 * inv; al[tid][1] = e1 * inv;
    al[tid][2] = e2 * inv; al[tid][3] = e3 * inv;
  }
  __syncthreads();
  // --- bias_eff: block 0 only ---
  if (blockIdx.x == 0) {
    #pragma unroll
    for (int b = 0; b < 32; ++b) {
      float s = 0.f;
      #pragma unroll
      for (int k = 0; k < 4; ++k) s += al[b][k] * bias[k * 256 + tid];
      bias_eff[b * 256 + tid] = s;
    }
  }
  // --- fold: one thread per weff fragment position, loop over 32 b ---
  int gid = blockIdx.x * 256 + tid;   // 28672 = 2 cb * 56 step * 4 ct * 64
  int cb = gid / 14336;
  int r = gid - cb * 14336;
  int step = r >> 8;                  // 0..55
  int ct = (r >> 6) & 3;
  int lpos = r & 63;
  int s7 = step >> 3, slice = step & 7;
  int cout = cb * 128 + ct * 32 + (lpos & 31);
  int ci0 = slice * 16 + (lpos >> 5) * 8;
  float wv[4][8];
  #pragma unroll
  for (int k = 0; k < 4; ++k) {
    const float* src = w + ((size_t)(k * 256 + cout) * 128 + ci0) * 7 + s7;
    #pragma unroll
    for (int j = 0; j < 8; ++j) wv[k][j] = src[j * 7];
  }
  unsigned short* dst = weff + (size_t)gid * 8;
  #pragma unroll 4
  for (int b = 0; b < 32; ++b) {
    float a0 = al[b][0], a1 = al[b][1], a2 = al[b][2], a3 = al[b][3];
    unsigned short h[8];
    #pragma unroll
    for (int j = 0; j < 8; ++j)
      h[j] = f2bf(a0 * wv[0][j] + a1 * wv[1][j] + a2 * wv[2][j] + a3 * wv[3][j]);
    uint4 o;
    o.x = (unsigned)h[0] | ((unsigned)h[1] << 16);
    o.y = (unsigned)h[2] | ((unsigned)h[3] << 16);
    o.z = (unsigned)h[4] | ((unsigned)h[5] << 16);
    o.w = (unsigned)h[6] | ((unsigned)h[7] << 16);
    *(uint4*)(dst + (size_t)b * 229376) = o;   // b stride: 28672 short8
  }
}

// ---------------------------------------------------------------------------
// Kernel 3: conv. Block = one (b,tb): stages x fp32->bf16 LDS tile
// [g=16][262 rows][8ci] (halo zero-padded), then implicit-GEMM conv for BOTH
// cout halves reusing the tile. 4 waves 2x2 (wm: cout-64, wn: t-128), each
// 64x128 via 2x4 mfma_32x32x16 per K-16 slice. W streamed global->VGPR with
// one-step-ahead prefetch. XCD swizzle clusters same-b blocks.
// ---------------------------------------------------------------------------
__global__ __launch_bounds__(256, 2) void k_conv3(
    const float* __restrict__ x, const unsigned short* __restrict__ weff,
    const float* __restrict__ bias_eff, float* __restrict__ out) {
  __shared__ __align__(16) unsigned short xs[16 * 262 * 8];  // 67,072 B
  int phys = blockIdx.x;                         // 512 = 32 b * 16 tb
  int logical = (phys & 7) * 64 + (phys >> 3);   // bijective: same-b per XCD
  int b = logical >> 4, tb = logical & 15;
  int tid = threadIdx.x;
  int t00 = tb << 8;

  // ---- stage x tile: rows hold t = t00-3+row, zero outside [0,4096) ----
  {
    const float* xbase = x + (size_t)b * 128 * 4096;
    int xrow = t00 - 3 + tid;
    bool valid = (unsigned)xrow < 4096u;
    #pragma unroll
    for (int g = 0; g < 16; ++g) {
      float f[8];
      #pragma unroll
      for (int u = 0; u < 8; ++u)
        f[u] = valid ? xbase[(size_t)(g * 8 + u) * 4096 + xrow] : 0.f;
      uint4 o;
      o.x = (unsigned)f2bf(f[0]) | ((unsigned)f2bf(f[1]) << 16);
      o.y = (unsigned)f2bf(f[2]) | ((unsigned)f2bf(f[3]) << 16);
      o.z = (unsigned)f2bf(f[4]) | ((unsigned)f2bf(f[5]) << 16);
      o.w = (unsigned)f2bf(f[6]) | ((unsigned)f2bf(f[7]) << 16);
      *(uint4*)(&xs[(g * 262 + tid) * 8]) = o;
    }
    if (tid < 128) {
      int g = tid >> 3, r8 = tid & 7;
      if (r8 < 6) {
        int row2 = 256 + r8;
        int xrow2 = t00 - 3 + row2;
        bool v2 = (unsigned)xrow2 < 4096u;
        float f[8];
        #pragma unroll
        for (int u = 0; u < 8; ++u)
          f[u] = v2 ? xbase[(size_t)(g * 8 + u) * 4096 + xrow2] : 0.f;
        uint4 o;
        o.x = (unsigned)f2bf(f[0]) | ((unsigned)f2bf(f[1]) << 16);
        o.y = (unsigned)f2bf(f[2]) | ((unsigned)f2bf(f[3]) << 16);
        o.z = (unsigned)f2bf(f[4]) | ((unsigned)f2bf(f[5]) << 16);
        o.w = (unsigned)f2bf(f[6]) | ((unsigned)f2bf(f[7]) << 16);
        *(uint4*)(&xs[(g * 262 + row2) * 8]) = o;
      }
    }
  }
  __syncthreads();

  // ---- conv: two cb passes over the same x tile ----
  int wave = tid >> 6, lane = tid & 63;
  int l31 = lane & 31, lhi = lane >> 5;
  int wm = wave & 1, wn = wave >> 1;
  const short8* wb8 = (const short8*)weff + (size_t)b * 28672 + lane;

  for (int cb = 0; cb < 2; ++cb) {
    f32x16 acc[2][4];
    #pragma unroll
    for (int mi = 0; mi < 2; ++mi)
      #pragma unroll
      for (int ni = 0; ni < 4; ++ni)
        acc[mi][ni] = (f32x16)(0.f);

    // A-fragments: this wave covers cout wm*64 + ct*32; ct = wm*2 + mi
    const short8* wfrag = wb8 + (size_t)cb * 14336 + (wm * 2) * 64;
    short8 av[2];
    #pragma unroll
    for (int mi = 0; mi < 2; ++mi) av[mi] = wfrag[mi * 64];

    #pragma unroll 2
    for (int step = 0; step < 56; ++step) {
      int s = step >> 3, slice = step & 7;
      short8 avn[2];
      if (step < 55) {
        #pragma unroll
        for (int mi = 0; mi < 2; ++mi)
          avn[mi] = wfrag[(step + 1) * 256 + mi * 64];
      }
      short8 bv[4];
      int prow = (slice * 2 + lhi) * 262 + s;
      #pragma unroll
      for (int ni = 0; ni < 4; ++ni) {
        int tt = wn * 128 + ni * 32 + l31;
        bv[ni] = *(const short8*)(&xs[(size_t)(prow + tt) * 8]);
      }
      #pragma unroll
      for (int mi = 0; mi < 2; ++mi)
        #pragma unroll
        for (int ni = 0; ni < 4; ++ni)
          acc[mi][ni] = __builtin_amdgcn_mfma_f32_32x32x16_bf16(
              av[mi], bv[ni], acc[mi][ni], 0, 0, 0);
      #pragma unroll
      for (int mi = 0; mi < 2; ++mi) av[mi] = avn[mi];
    }

    // epilogue: D layout col(lane&31)=t, row=(r&3)+8*(r>>2)+4*lhi=cout-in-32
    int crow0 = b * 256 + cb * 128;
    #pragma unroll
    for (int mi = 0; mi < 2; ++mi) {
      #pragma unroll
      for (int r = 0; r < 16; ++r) {
        int c = wm * 64 + mi * 32 + (r & 3) + 8 * (r >> 2) + 4 * lhi;
        float bb = bias_eff[crow0 + c];
        float* orow = out + (size_t)(crow0 + c) * 4096 + t00;
        #pragma unroll
        for (int ni = 0; ni < 4; ++ni)
          orow[wn * 128 + ni * 32 + l31] = acc[mi][ni][r] + bb;
      }
    }
  }
}

extern "C" void kernel_launch(void* const* d_in, const int* in_sizes, int n_in,
                              void* d_out, int out_size, void* d_ws, size_t ws_size,
                              hipStream_t stream) {
  const float* x    = (const float*)d_in[0];
  const float* w    = (const float*)d_in[1];
  const float* bias = (const float*)d_in[2];
  const float* rw   = (const float*)d_in[3];
  const float* rb   = (const float*)d_in[4];
  float* out = (float*)d_out;
  char* ws = (char*)d_ws;
  unsigned short* weff = (unsigned short*)(ws + WEFF_OFF);
  float* pooled        = (float*)(ws + POOLED_OFF);
  float* bias_eff      = (float*)(ws + BEFF_OFF);

  hipLaunchKernelGGL(k_pool,  dim3(4096), dim3(256), 0, stream, x, pooled);
  hipLaunchKernelGGL(k_fold,  dim3(112),  dim3(256), 0, stream,
                     w, pooled, rw, rb, bias, weff, bias_eff);
  hipLaunchKernelGGL(k_conv3, dim3(512),  dim3(256), 0, stream,
                     x, weff, bias_eff, out);
}